// Round 7
// baseline (91.475 us; speedup 1.0000x reference)
//
#include <hip/hip_runtime.h>

#define NB 256   // num_basis
#define NO 32    // output_size
#define NI 128   // input_size
// pairs = NB*NO = 8192; Lambda_inv = 512 MB fp32 (streamed once, no reuse)

typedef float f32x4 __attribute__((ext_vector_type(4)));

__device__ __forceinline__ float dot4(f32x4 a, f32x4 b) {
    return fmaf(a.x, b.x, fmaf(a.y, b.y, fmaf(a.z, b.z, a.w * b.w)));
}

__global__ __launch_bounds__(256, 4) void rbf_quad_kernel(
    const float* __restrict__ x,        // [NI]
    const float* __restrict__ centers,  // [NB][NO][NI]
    const float* __restrict__ Lam,      // [NB][NO][NI][NI]
    float* __restrict__ rbf)            // [NB*NO]
{
    __shared__ float diff_lds[4][NI];
    const int lane = threadIdx.x & 63;
    const int wid  = threadIdx.x >> 6;
    const int p    = blockIdx.x * 4 + wid;   // pair index = b*NO + o

    // diff = x - centers[p], 2 elements per lane -> LDS
    const float2 xv = *(const float2*)(x + 2 * lane);
    const float2 cv = *(const float2*)(centers + (size_t)p * NI + 2 * lane);
    *(float2*)(&diff_lds[wid][2 * lane]) = make_float2(xv.x - cv.x, xv.y - cv.y);
    __syncthreads();

    // Lane owns columns c..c+3 (held in dj); half-wave h picks the row
    // within each 2-row slab.
    const int c = 4 * (lane & 31);
    const int h = lane >> 5;
    const f32x4 dj = *(const f32x4*)(&diff_lds[wid][c]);
    const float* dlds = diff_lds[wid];

    const f32x4* __restrict__ Lq = (const f32x4*)(Lam + (size_t)p * (NI * NI));

    // All-nontemporal stream (512 MB read exactly once; LLC retention was
    // falsified in R4/R6 — MALL is memory-side, nt only skips L2 alloc).
    // 4 independent loads + 4 independent FMA chains per iteration
    // (4 KiB/wave/iter = rows 8it..8it+7); unroll 4 -> up to 16 loads in
    // flight per wave within the 128-VGPR budget of launch_bounds(256,4).
    float acc0 = 0.0f, acc1 = 0.0f, acc2 = 0.0f, acc3 = 0.0f;
    #pragma unroll 4
    for (int it = 0; it < NI / 8; ++it) {
        const f32x4* pb = Lq + (size_t)it * 256 + lane;
        const f32x4 L0 = __builtin_nontemporal_load(pb);
        const f32x4 L1 = __builtin_nontemporal_load(pb + 64);
        const f32x4 L2 = __builtin_nontemporal_load(pb + 128);
        const f32x4 L3 = __builtin_nontemporal_load(pb + 192);
        const float di0 = dlds[8 * it + 0 + h];
        const float di1 = dlds[8 * it + 2 + h];
        const float di2 = dlds[8 * it + 4 + h];
        const float di3 = dlds[8 * it + 6 + h];
        acc0 = fmaf(di0, dot4(L0, dj), acc0);
        acc1 = fmaf(di1, dot4(L1, dj), acc1);
        acc2 = fmaf(di2, dot4(L2, dj), acc2);
        acc3 = fmaf(di3, dot4(L3, dj), acc3);
    }

    float acc = (acc0 + acc1) + (acc2 + acc3);
    #pragma unroll
    for (int off = 32; off; off >>= 1) acc += __shfl_xor(acc, off);

    if (lane == 0) rbf[p] = expf(-0.5f * acc);
}

__global__ __launch_bounds__(256) void rbf_policy_kernel(
    const float* __restrict__ weights,  // [NO][NB]
    const float* __restrict__ rbf,      // [NB][NO]  (indexed [b*NO + o])
    const float* __restrict__ bnds,     // [2][NO]
    float* __restrict__ out)            // [NO]
{
    const int o = blockIdx.x;
    const int t = threadIdx.x;          // t == b

    float v = weights[o * NB + t] * rbf[t * NO + o];

    #pragma unroll
    for (int off = 32; off; off >>= 1) v += __shfl_xor(v, off);

    __shared__ float part[4];
    if ((t & 63) == 0) part[t >> 6] = v;
    __syncthreads();

    if (t == 0) {
        const float s   = part[0] + part[1] + part[2] + part[3];
        const float pol = tanhf(s);
        const float lo  = bnds[o];
        const float hi  = bnds[NO + o];
        out[o] = (pol + 1.0f) * 0.5f * (hi - lo) + lo;
    }
}

extern "C" void kernel_launch(void* const* d_in, const int* in_sizes, int n_in,
                              void* d_out, int out_size, void* d_ws, size_t ws_size,
                              hipStream_t stream) {
    const float* x       = (const float*)d_in[0];
    const float* weights = (const float*)d_in[1];
    const float* centers = (const float*)d_in[2];
    const float* Lam     = (const float*)d_in[3];
    const float* bnds    = (const float*)d_in[4];
    float* out = (float*)d_out;
    float* rbf = (float*)d_ws;   // NB*NO floats = 32 KB

    rbf_quad_kernel<<<2048, 256, 0, stream>>>(x, centers, Lam, rbf);
    rbf_policy_kernel<<<NO, NB, 0, stream>>>(weights, rbf, bnds, out);
}